// Round 14
// baseline (10962.561 us; speedup 1.0000x reference)
//
#include <hip/hip_runtime.h>
#include <math.h>

#define BB 128
#define SS 72
#define NITER 16
#define D_IN 512
#define D_MODEL 1024
#define MEMN 25
#define HEADS 8
#define DHH 64
#define N_SO 256
#define N_SA 64
#define SA_SZ 2080
#define SO_SZ 32896
#define NCLS 1968
#define TED 128
#define VOCAB 32
#define ROWS (BB*SS)
#define TRACE_SLOTS (MEMN + NITER)   /* 41 */
#define QPAD 2176                    /* SA_SZ padded to 17*128 */

/* big-GEMM (sync_o @ out_w) tiling */
#define BGN 64
#define BGKS 16
#define BGKLEN 2056
#define BGSTEPS 33
#define NPART 1984
#define WHLD 1984
#define WCHUNKS 124
#define SYNZ 6
#define NB_BIG 496                   /* 31*16 bigemm blocks in AB1 */
#define NB_Q 256                     /* 2*32*4 gemmq blocks in AB1 */
#define NB_ATTN 1024                 /* BB*HEADS attn blocks in AB2 */

typedef _Float16 half_t;
typedef _Float16 half8 __attribute__((ext_vector_type(8)));
typedef float f32x4v __attribute__((ext_vector_type(4)));

__device__ __forceinline__ float sigmoidf_(float x){ return 1.f/(1.f+expf(-x)); }

template<int NT>
__device__ __forceinline__ float bsumN(float v, float* red){
  int tid = threadIdx.x; red[tid] = v; __syncthreads();
#pragma unroll
  for (int s = NT/2; s > 0; s >>= 1){ if (tid < s) red[tid] += red[tid+s]; __syncthreads(); }
  float r = red[0]; __syncthreads(); return r;
}

__device__ __forceinline__ long triu_off(int n, int i){
  return (long)i*n - ((long)i*(i-1))/2;
}

__device__ __forceinline__ int swzA(int b){ return b ^ (((b>>9)&1)<<5); }

// ---------------- setup kernels ----------------
__global__ void k_conv(const float* __restrict__ src, half_t* __restrict__ dst, int n){
  int gid = blockIdx.x*256 + threadIdx.x;
  if (gid < n) dst[gid] = (half_t)src[gid];
}

// merged fp32->fp16 weight conversions
#define CV0 (VOCAB*TED)
#define CV1 (CV0 + TED*D_IN)
#define CV2 (CV1 + D_IN*D_IN)
#define CV3 (CV2 + D_IN*D_IN)
#define CV4 (CV3 + D_IN*D_IN)
#define CV5 (CV4 + D_IN*D_IN)
#define CV6 (CV5 + D_IN*2048)
#define CV7 (CV6 + QPAD*D_IN)
__global__ void k_convall(const float* __restrict__ emb, const float* __restrict__ kv_w,
                          const float* __restrict__ in_proj_w,
                          const float* __restrict__ out_proj_w,
                          const float* __restrict__ syn_w, const float* __restrict__ q_w,
                          half_t* __restrict__ embh, half_t* __restrict__ kvwh,
                          half_t* __restrict__ Wkh, half_t* __restrict__ Wvh,
                          half_t* __restrict__ Wqh, half_t* __restrict__ oph,
                          half_t* __restrict__ synth, half_t* __restrict__ qwh){
  int gid = blockIdx.x*256 + threadIdx.x;
  if (gid < CV0){ embh[gid] = (half_t)emb[gid]; return; }
  if (gid < CV1){ int i = gid - CV0; kvwh[i] = (half_t)kv_w[i]; return; }
  if (gid < CV2){ int i = gid - CV1; int r = i >> 9, c = i & 511;
                  Wkh[i] = (half_t)in_proj_w[(size_t)r*1536 + 512 + c]; return; }
  if (gid < CV3){ int i = gid - CV2; int r = i >> 9, c = i & 511;
                  Wvh[i] = (half_t)in_proj_w[(size_t)r*1536 + 1024 + c]; return; }
  if (gid < CV4){ int i = gid - CV3; int r = i >> 9, c = i & 511;
                  Wqh[i] = (half_t)in_proj_w[(size_t)r*1536 + c]; return; }
  if (gid < CV5){ int i = gid - CV4; oph[i] = (half_t)out_proj_w[i]; return; }
  if (gid < CV6){ int i = gid - CV5; synth[i] = (half_t)syn_w[i]; return; }
  if (gid < CV7){ int i = gid - CV6; int r = i >> 9;
                  qwh[i] = (r < SA_SZ) ? (half_t)q_w[i] : (half_t)0.f; return; }
}

__global__ void k_convsyn(const float* __restrict__ Wf2, const float* __restrict__ syn_w,
                          half_t* __restrict__ Wsynh){
  int gid = blockIdx.x*256 + threadIdx.x;
  if (gid >= 1536*2048) return;
  Wsynh[gid] = (half_t)((gid < 512*2048) ? Wf2[gid] : syn_w[gid]);
}

__global__ void k_embed_h(const int* __restrict__ x, const half_t* __restrict__ embh,
                          half_t* __restrict__ out){
  int gid = blockIdx.x*256 + threadIdx.x;
  if (gid >= ROWS*(TED/8)) return;
  int row = gid >> 4, c0 = (gid & 15)*8;
  *(half8*)(out + (size_t)row*TED + c0) = *(const half8*)(embh + (size_t)x[row]*TED + c0);
}

__global__ void k_init_pairs(int n, int npairs, const float* __restrict__ decay,
                             int2* __restrict__ pairs, float* __restrict__ rv){
  int p = blockIdx.x*256 + threadIdx.x;
  if (p >= npairs) return;
  double nn = (double)n;
  double disc = (2.0*nn+1.0)*(2.0*nn+1.0) - 8.0*(double)p;
  int i = (int)floor(((2.0*nn+1.0) - sqrt(disc))*0.5);
  if (i < 0) i = 0; if (i > n-1) i = n-1;
  while (i+1 < n && triu_off(n, i+1) <= (long)p) i++;
  while (i > 0 && triu_off(n, i) > (long)p) i--;
  int j = i + (int)((long)p - triu_off(n, i));
  pairs[p] = make_int2(i, j);
  float dc = decay[p]; dc = fminf(fmaxf(dc, 0.f), 15.f);
  rv[p] = expf(-dc);
}

__global__ void k_init_act(const float* __restrict__ sa, float* __restrict__ act,
                           half_t* __restrict__ Ah16){
  int gid = blockIdx.x*256 + threadIdx.x;
  if (gid >= BB*D_MODEL) return;
  int b = gid >> 10, d = gid & 1023;
  float v = sa[d];
  act[gid] = v;
  Ah16[(size_t)b*1536 + 512 + d] = (half_t)v;
}

__global__ void k_zero(float* __restrict__ p, int n){
  int gid = blockIdx.x*256 + threadIdx.x;
  if (gid < n) p[gid] = 0.f;
}

__global__ void k_init_trace(const float* __restrict__ st, float* __restrict__ trace){
  int gid = blockIdx.x*256 + threadIdx.x;
  if (gid >= BB*MEMN*D_MODEL) return;
  int d = gid & 1023;
  int m = (gid >> 10) % MEMN;
  int b = (gid >> 10) / MEMN;
  trace[(size_t)b*TRACE_SLOTS*D_MODEL + (size_t)m*D_MODEL + d] = st[d*MEMN + m];
}

__global__ void k_init_ao(const float* __restrict__ sa, const int2* __restrict__ pairs,
                          float* __restrict__ ao){
  int p = blockIdx.x*256 + threadIdx.x;
  if (p >= SO_SZ) return;
  int b = blockIdx.y;
  int2 ij = pairs[p];
  ao[(size_t)b*SO_SZ + p] = sa[ij.x]*sa[ij.y];
}

__global__ void k_convw(const float* __restrict__ W, half_t* __restrict__ Wh){
  int gid = blockIdx.x*256 + threadIdx.x;
  if (gid >= SO_SZ*WCHUNKS) return;
  int row = gid / WCHUNKS, ch = gid - row*WCHUNKS;
  int c0 = ch*16;
  half_t* dst = Wh + (size_t)row*WHLD + c0;
  if (ch < 123){
    const float4* src = (const float4*)(W + (size_t)row*NCLS + c0);
    float4 f0 = src[0], f1 = src[1], f2 = src[2], f3 = src[3];
    half8 h0, h1;
    h0[0]=(half_t)f0.x; h0[1]=(half_t)f0.y; h0[2]=(half_t)f0.z; h0[3]=(half_t)f0.w;
    h0[4]=(half_t)f1.x; h0[5]=(half_t)f1.y; h0[6]=(half_t)f1.z; h0[7]=(half_t)f1.w;
    h1[0]=(half_t)f2.x; h1[1]=(half_t)f2.y; h1[2]=(half_t)f2.z; h1[3]=(half_t)f2.w;
    h1[4]=(half_t)f3.x; h1[5]=(half_t)f3.y; h1[6]=(half_t)f3.z; h1[7]=(half_t)f3.w;
    *(half8*)dst = h0; *(half8*)(dst+8) = h1;
  } else {
    half8 zz;
#pragma unroll
    for (int j = 0; j < 8; j++) zz[j] = (half_t)0.f;
    *(half8*)dst = zz; *(half8*)(dst+8) = zz;
  }
}

__global__ void k_colsumP(const float* __restrict__ vec, const float* __restrict__ W,
                          int ldw, float* __restrict__ part, int N){
  int col = blockIdx.x*256 + threadIdx.x;
  int kz = blockIdx.y;
  if (col >= N) return;
  float s = 0.f;
#pragma unroll
  for (int k = kz*32; k < kz*32 + 32; k++)
    s = fmaf(vec[k], W[(size_t)k*ldw + col], s);
  part[(size_t)kz*N + col] = s;
}

__global__ void k_colsumR(const float* __restrict__ part, const float* __restrict__ addb,
                          float* __restrict__ out, int N){
  int col = blockIdx.x*256 + threadIdx.x;
  if (col >= N) return;
  float s = addb[col];
#pragma unroll
  for (int z = 0; z < 16; z++) s += part[(size_t)z*N + col];
  out[col] = s;
}

// ---- fp16 MFMA GEMM (generalized, setup): C = Ah @ Wh16 + bias ----
__global__ __launch_bounds__(256)
void k_pgemm(const half_t* __restrict__ Ah, int ldah,
             const half_t* __restrict__ Wh16, int ldw, const float* __restrict__ bias,
             float* __restrict__ C, int ldc, int ksteps){
  __shared__ half_t As[2][128*64];
  __shared__ half_t Ws[2][64*66];
  const int tid = threadIdx.x;
  const int nb0 = blockIdx.x * 64;
  const int row0 = blockIdx.y * 128;
  const int l = tid & 63, wv = tid >> 6;
  const int mw = (wv >> 1) * 64, nw = (wv & 1) * 32;
  const int c = l & 15, g = l >> 4;

  f32x4v acc[4][2];
#pragma unroll
  for (int i = 0; i < 4; i++)
#pragma unroll
    for (int j2 = 0; j2 < 2; j2++)
#pragma unroll
      for (int r = 0; r < 4; r++) acc[i][j2][r] = 0.f;

  auto stage = [&](int s, int buf){
#pragma unroll
    for (int it = 0; it < 4; it++){
      int ch = tid + it*256;
      int m = ch >> 3, kl = (ch & 7)*8;
      half8 v = *(const half8*)(Ah + (size_t)(row0+m)*ldah + s*64 + kl);
      *(half8*)((char*)(&As[buf][0]) + swzA(ch*16)) = v;
    }
    {
      int k = tid >> 2, cs = (tid & 3) * 16;
      const half_t* wr = Wh16 + (size_t)(s*64 + k) * ldw + nb0 + cs;
      char* dst = (char*)(&Ws[buf][0]) + (size_t)(k*66 + cs) * 2;
      union { half8 v; unsigned int u[4]; } p0, p1;
      p0.v = *(const half8*)wr; p1.v = *(const half8*)(wr + 8);
#pragma unroll
      for (int q = 0; q < 4; q++){
        ((unsigned int*)dst)[q]        = p0.u[q];
        ((unsigned int*)(dst + 16))[q] = p1.u[q];
      }
    }
  };

  stage(0, 0);
  __syncthreads();
  for (int s = 0; s < ksteps; s++){
    int buf = s & 1;
    if (s + 1 < ksteps) stage(s+1, buf^1);
#pragma unroll
    for (int h = 0; h < 2; h++){
      half8 a8[4];
#pragma unroll
      for (int mb = 0; mb < 4; mb++)
        a8[mb] = *(const half8*)((const char*)(&As[buf][0]) +
                   swzA(((mw + mb*16 + c)*64 + h*32 + g*8)*2));
#pragma unroll
      for (int nb = 0; nb < 2; nb++){
        half8 b8;
        const half_t* wp = &Ws[buf][(h*32 + g*8)*66 + nw + nb*16 + c];
#pragma unroll
        for (int j = 0; j < 8; j++) b8[j] = wp[j*66];
#pragma unroll
        for (int mb = 0; mb < 4; mb++)
          acc[mb][nb] = __builtin_amdgcn_mfma_f32_16x16x32_f16(a8[mb], b8, acc[mb][nb], 0, 0, 0);
      }
    }
    __syncthreads();
  }
#pragma unroll
  for (int mb = 0; mb < 4; mb++)
#pragma unroll
    for (int nb = 0; nb < 2; nb++){
      int m = mw + mb*16 + g*4;
      int n = nb0 + nw + nb*16 + c;
      float bv = bias ? bias[n] : 0.f;
#pragma unroll
      for (int r = 0; r < 4; r++)
        C[(size_t)(row0 + m + r) * ldc + n] = acc[mb][nb][r] + bv;
    }
}

// ---- syn fp16 MFMA GEMM ----
__global__ __launch_bounds__(256)
void k_syn16(const half_t* __restrict__ Ah, const half_t* __restrict__ Wh16,
             float* __restrict__ outp){
  __shared__ half_t As[2][128*64];
  __shared__ half_t Ws[2][64*66];
  const int tid = threadIdx.x;
  const int nb0 = blockIdx.x * 64;
  const int z = blockIdx.y;
  const int l = tid & 63, wv = tid >> 6;
  const int mw = (wv >> 1) * 64, nw = (wv & 1) * 32;
  const int c = l & 15, g = l >> 4;
  const int kbase = z * 256;

  f32x4v acc[4][2];
#pragma unroll
  for (int i = 0; i < 4; i++)
#pragma unroll
    for (int j2 = 0; j2 < 2; j2++)
#pragma unroll
      for (int r = 0; r < 4; r++) acc[i][j2][r] = 0.f;

  auto stage = [&](int s, int buf){
#pragma unroll
    for (int it = 0; it < 4; it++){
      int ch = tid + it*256;
      int m = ch >> 3, kl = (ch & 7)*8;
      half8 v = *(const half8*)(Ah + (size_t)m*1536 + kbase + s*64 + kl);
      *(half8*)((char*)(&As[buf][0]) + swzA(ch*16)) = v;
    }
    {
      int k = tid >> 2, cs = (tid & 3) * 16;
      const half_t* wr = Wh16 + (size_t)(kbase + s*64 + k) * 2048 + nb0 + cs;
      char* dst = (char*)(&Ws[buf][0]) + (size_t)(k*66 + cs) * 2;
      union { half8 v; unsigned int u[4]; } p0, p1;
      p0.v = *(const half8*)wr; p1.v = *(const half8*)(wr + 8);
#pragma unroll
      for (int q = 0; q < 4; q++){
        ((unsigned int*)dst)[q]        = p0.u[q];
        ((unsigned int*)(dst + 16))[q] = p1.u[q];
      }
    }
  };

  stage(0, 0);
  __syncthreads();
  for (int s = 0; s < 4; s++){
    int buf = s & 1;
    if (s + 1 < 4) stage(s+1, buf^1);
#pragma unroll
    for (int h = 0; h < 2; h++){
      half8 a8[4];
#pragma unroll
      for (int mb = 0; mb < 4; mb++)
        a8[mb] = *(const half8*)((const char*)(&As[buf][0]) +
                   swzA(((mw + mb*16 + c)*64 + h*32 + g*8)*2));
#pragma unroll
      for (int nb = 0; nb < 2; nb++){
        half8 b8;
        const half_t* wp = &Ws[buf][(h*32 + g*8)*66 + nw + nb*16 + c];
#pragma unroll
        for (int j = 0; j < 8; j++) b8[j] = wp[j*66];
#pragma unroll
        for (int mb = 0; mb < 4; mb++)
          acc[mb][nb] = __builtin_amdgcn_mfma_f32_16x16x32_f16(a8[mb], b8, acc[mb][nb], 0, 0, 0);
      }
    }
    __syncthreads();
  }
  float* pz = outp + (size_t)z * BB * 2048;
#pragma unroll
  for (int mb = 0; mb < 4; mb++)
#pragma unroll
    for (int nb = 0; nb < 2; nb++){
      int m = mw + mb*16 + g*4;
      int n = nb0 + nw + nb*16 + c;
#pragma unroll
      for (int r = 0; r < 4; r++)
        pz[(size_t)(m + r) * 2048 + n] = acc[mb][nb][r];
    }
}

// ================= device bodies =================

__device__ __forceinline__ void dev_bigemm(int bx, int z, int tid,
    half_t* AsBuf, half_t* WsBuf,
    const half_t* __restrict__ Ah, const half_t* __restrict__ Wh,
    float* __restrict__ part){
  const int nb0 = bx * BGN;
  const int l = tid & 63, wv = tid >> 6;
  const int mw = (wv >> 1) * 64, nw = (wv & 1) * 32;
  const int c = l & 15, g = l >> 4;
  const int k0 = z * BGKLEN;

  f32x4v acc[4][2];
#pragma unroll
  for (int i = 0; i < 4; i++)
#pragma unroll
    for (int j2 = 0; j2 < 2; j2++)
#pragma unroll
      for (int r = 0; r < 4; r++) acc[i][j2][r] = 0.f;

  auto stage = [&](int s, int buf){
    const int kv = min(64, BGKLEN - s*64);
    half_t* As = AsBuf + buf*8192;
    half_t* Ws = WsBuf + buf*4224;
#pragma unroll
    for (int it = 0; it < 4; it++){
      int ch = tid + it*256;
      int m = ch >> 3, kg = ch & 7, kl = kg*8;
      half8 v;
      if (kl < kv) v = *(const half8*)(Ah + (size_t)m*SO_SZ + k0 + s*64 + kl);
      else {
#pragma unroll
        for (int j = 0; j < 8; j++) v[j] = (half_t)0.f;
      }
      *(half8*)((char*)As + swzA(ch*16)) = v;
    }
    {
      int k = tid >> 2, cs = (tid & 3) * 16;
      const half_t* wr = Wh + (size_t)(k0 + s*64 + k) * WHLD + nb0 + cs;
      char* dst = (char*)Ws + (size_t)(k*66 + cs) * 2;
      union { half8 v; unsigned int u[4]; } p0, p1;
      if (k < kv){ p0.v = *(const half8*)wr; p1.v = *(const half8*)(wr + 8); }
      else {
#pragma unroll
        for (int j = 0; j < 8; j++){ p0.v[j] = (half_t)0.f; p1.v[j] = (half_t)0.f; }
      }
#pragma unroll
      for (int q = 0; q < 4; q++){
        ((unsigned int*)dst)[q]        = p0.u[q];
        ((unsigned int*)(dst + 16))[q] = p1.u[q];
      }
    }
  };

  stage(0, 0);
  __syncthreads();
  for (int s = 0; s < BGSTEPS; s++){
    int buf = s & 1;
    if (s + 1 < BGSTEPS) stage(s+1, buf^1);
    half_t* As = AsBuf + buf*8192;
    half_t* Ws = WsBuf + buf*4224;
#pragma unroll
    for (int h = 0; h < 2; h++){
      half8 a8[4];
#pragma unroll
      for (int mb = 0; mb < 4; mb++)
        a8[mb] = *(const half8*)((const char*)As +
                   swzA(((mw + mb*16 + c)*64 + h*32 + g*8)*2));
#pragma unroll
      for (int nb = 0; nb < 2; nb++){
        half8 b8;
        const half_t* wp = Ws + (h*32 + g*8)*66 + nw + nb*16 + c;
#pragma unroll
        for (int j = 0; j < 8; j++) b8[j] = wp[j*66];
#pragma unroll
        for (int mb = 0; mb < 4; mb++)
          acc[mb][nb] = __builtin_amdgcn_mfma_f32_16x16x32_f16(a8[mb], b8, acc[mb][nb], 0, 0, 0);
      }
    }
    __syncthreads();
  }
  float* pz = part + (size_t)z * 128 * NPART;
#pragma unroll
  for (int mb = 0; mb < 4; mb++)
#pragma unroll
    for (int nb = 0; nb < 2; nb++){
      int m = mw + mb*16 + g*4;
      int n = nb0 + nw + nb*16 + c;
#pragma unroll
      for (int r = 0; r < 4; r++)
        pz[(size_t)(m + r) * NPART + n] = acc[mb][nb][r];
    }
}

__device__ __forceinline__ void dev_gemmq(int gx, int gy, int z, int tid, float* AsF,
    const float* __restrict__ act,
    const float* __restrict__ r_a, const int2* __restrict__ pairsA,
    const float* __restrict__ aaIn, float* __restrict__ aaOut,
    const half_t* __restrict__ Wh, float* __restrict__ qpart, int t){
  constexpr int KC = 32;
  const int col = gx*256 + tid;
  const int row0 = gy*4;
  const int kstart = z*544;
  const int kend = min(SA_SZ, kstart + 544);
  const bool writer = (gx == 0);
  float acc[4] = {0.f,0.f,0.f,0.f};
  for (int kk = kstart; kk < kend; kk += KC){
    __syncthreads();
    if (tid < 4*KC){
      int r = tid >> 5, k = tid & 31;
      int p = kk + k;
      int b = row0 + r;
      int2 ij = pairsA[p];
      const float* ab = act + (size_t)b*D_MODEL + (D_MODEL - N_SA);
      float rv = r_a[p];
      size_t idx = (size_t)b*SA_SZ + p;
      float a = fmaf(rv, aaIn[idx], ab[ij.x]*ab[ij.y]);
      if (writer) aaOut[idx] = a;
      float bb = 0.f;
      for (int i = 0; i <= t; i++) bb = fmaf(rv, bb, 1.f);
      AsF[r*KC + k] = a / sqrtf(bb);
    }
    __syncthreads();
#pragma unroll
    for (int k = 0; k < KC; k++){
      float w = (float)Wh[(size_t)(kk+k)*D_IN + col];
#pragma unroll
      for (int r = 0; r < 4; r++) acc[r] = fmaf(AsF[r*KC + k], w, acc[r]);
    }
  }
#pragma unroll
  for (int r = 0; r < 4; r++)
    qpart[(size_t)z*BB*D_IN + (size_t)(row0+r)*D_IN + col] = acc[r];
}

__device__ __forceinline__ void dev_attn(int bh, int tid,
    float* qs, float* attnv, float* red,
    const float* __restrict__ qpart, const float* __restrict__ bqf,
    const float* __restrict__ Km, const float* __restrict__ Vm,
    float* __restrict__ o, half_t* __restrict__ Ah16){
  const int b = bh >> 3, h = bh & 7;
  if (tid < DHH){
    int d = h*DHH + tid;
    float qv = bqf[d];
#pragma unroll
    for (int z = 0; z < 4; z++) qv += qpart[(size_t)z*BB*D_IN + (size_t)b*D_IN + d];
    qs[tid] = qv;
  }
  __syncthreads();
  float sc = -1e30f;
  if (tid < SS){
    const float* kp = Km + ((size_t)(b*SS+tid)*HEADS + h)*DHH;
    float d = 0.f;
#pragma unroll
    for (int i = 0; i < DHH; i++) d = fmaf(qs[i], kp[i], d);
    sc = d * 0.125f;
  }
  red[tid] = sc; __syncthreads();
  for (int s2 = 64; s2 > 0; s2 >>= 1){ if (tid < s2) red[tid] = fmaxf(red[tid], red[tid+s2]); __syncthreads(); }
  float m = red[0]; __syncthreads();
  float e = (tid < SS) ? expf(sc - m) : 0.f;
  red[tid] = e; __syncthreads();
  for (int s2 = 64; s2 > 0; s2 >>= 1){ if (tid < s2) red[tid] += red[tid+s2]; __syncthreads(); }
  float inv = 1.f / red[0]; __syncthreads();
  if (tid < SS) attnv[tid] = e * inv;
  __syncthreads();
  if (tid < DHH){
    const float* vp = Vm + ((size_t)(b*SS)*HEADS + h)*DHH + tid;
    float acc = 0.f;
    for (int s2 = 0; s2 < SS; s2++) acc = fmaf(attnv[s2], vp[(size_t)s2*D_IN], acc);
    int d = h*DHH + tid;
    o[(size_t)b*D_IN + d] = acc;
    Ah16[(size_t)b*1536 + d] = (half_t)acc;
  }
}

__device__ __forceinline__ void dev_out128(int b, int tid, float* pred, float* red,
    const float* __restrict__ part, const float* __restrict__ outb,
    float* __restrict__ dout, int t){
  float lmax = -1e30f;
  for (int c = tid; c < NCLS; c += 128){
    float s = outb[c];
    const float* pp = part + (size_t)b*NPART + c;
#pragma unroll
    for (int z = 0; z < BGKS; z++) s += pp[(size_t)z*128*NPART];
    pred[c] = s;
    dout[((size_t)b*NCLS + c)*NITER + t] = s;
    lmax = fmaxf(lmax, s);
  }
  red[tid] = lmax; __syncthreads();
  for (int s2 = 64; s2 > 0; s2 >>= 1){ if (tid < s2) red[tid] = fmaxf(red[tid], red[tid+s2]); __syncthreads(); }
  float m = red[0]; __syncthreads();
  float se = 0.f;
  for (int c = tid; c < NCLS; c += 128) se += expf(pred[c]-m);
  float Z = bsumN<128>(se, red);
  float logZ = m + logf(Z);
  float ent = 0.f;
  for (int c = tid; c < NCLS; c += 128){ float lp = pred[c]-logZ; ent += expf(lp)*lp; }
  float E = bsumN<128>(ent, red);
  if (tid == 0){
    float ne = -E * (1.f/logf((float)NCLS));
    float* cp = dout + (size_t)BB*NCLS*NITER + (size_t)b*2*NITER + t;
    cp[0]     = ne;
    cp[NITER] = 1.f - ne;
  }
}

// neuron for one (b,d): trv fully unrolled (registers), newest slot from LDS vals
__device__ __forceinline__ void dev_neuron1(int b, int d, const float* __restrict__ vals,
    const float* __restrict__ trace,
    const float* __restrict__ tp1w, const float* __restrict__ tp1b,
    const float* __restrict__ tp2w, const float* __restrict__ tp2b,
    float* __restrict__ act, half_t* __restrict__ Ah16, int t){
  const float* tr = trace + (size_t)b*(TRACE_SLOTS*D_MODEL) + (size_t)(t+1)*D_MODEL + d;
  float trv[MEMN];
#pragma unroll
  for (int m = 0; m < MEMN-1; m++) trv[m] = tr[(size_t)m*D_MODEL];
  trv[MEMN-1] = vals[d];
  float o0 = tp2b[d*2+0], o1 = tp2b[d*2+1];
#pragma unroll
  for (int j = 0; j < 16; j++){
    const float* wpj = tp1w + (size_t)j*1024 + d;
    const float* wpg = tp1w + (size_t)(j+16)*1024 + d;
    float hj = tp1b[d*32 + j];
    float hg = tp1b[d*32 + j + 16];
#pragma unroll
    for (int m = 0; m < MEMN; m++){
      float tv = trv[m];
      hj = fmaf(tv, wpj[(size_t)m*32*1024], hj);
      hg = fmaf(tv, wpg[(size_t)m*32*1024], hg);
    }
    float hgv = hj * sigmoidf_(hg);
    o0 = fmaf(hgv, tp2w[(size_t)(j*2+0)*1024 + d], o0);
    o1 = fmaf(hgv, tp2w[(size_t)(j*2+1)*1024 + d], o1);
  }
  float v = o0 * sigmoidf_(o1);
  act[(size_t)b*D_MODEL + d] = v;
  Ah16[(size_t)b*1536 + 512 + d] = (half_t)v;
}

// ================= merged + standalone kernels =================

// AB1: blocks [0,496) bigemm(t-1); blocks [496,752) gemmq(t)
__global__ __launch_bounds__(256)
void k_AB1(const half_t* __restrict__ sync_oh, const half_t* __restrict__ Wh,
           float* __restrict__ part,
           const float* __restrict__ act, const float* __restrict__ r_a,
           const int2* __restrict__ pairsA,
           const float* __restrict__ aaIn, float* __restrict__ aaOut,
           const half_t* __restrict__ qfwh, float* __restrict__ qpart, int t){
  __shared__ half_t AsBuf[2*8192];
  __shared__ half_t WsBuf[2*4224];
  int blk = blockIdx.x, tid = threadIdx.x;
  if (blk < NB_BIG){
    dev_bigemm(blk % 31, blk / 31, tid, AsBuf, WsBuf, sync_oh, Wh, part);
  } else {
    int i = blk - NB_BIG;            // 256 blocks: z(4) x gx(2) x gy(32)
    dev_gemmq((i>>5)&1, i&31, i>>6, tid, (float*)AsBuf,
              act, r_a, pairsA, aaIn, aaOut, qfwh, qpart, t);
  }
}

// AB2 (128 threads): blocks [0,1024) attn(t); blocks [1024,1152) output(t-1)
__global__ __launch_bounds__(128)
void k_AB2(const float* __restrict__ qpart, const float* __restrict__ bqf,
           const float* __restrict__ Km, const float* __restrict__ Vm,
           float* __restrict__ o, half_t* __restrict__ Ah16,
           const float* __restrict__ part, const float* __restrict__ outb,
           float* __restrict__ dout, int tprev){
  __shared__ float sm[NCLS + 128];
  int blk = blockIdx.x, tid = threadIdx.x;
  if (blk < NB_ATTN){
    dev_attn(blk, tid, sm, sm + 64, sm + 136, qpart, bqf, Km, Vm, o, Ah16);
  } else {
    dev_out128(blk - NB_ATTN, tid, sm, sm + NCLS, part, outb, dout, tprev);
  }
}

// ---- merged GLU+LN+neuron tail: 512 threads, 2 elements per thread ----
__global__ void k_tail2(const float* __restrict__ synpart, const float* __restrict__ bias2,
                        const float* __restrict__ g, const float* __restrict__ bta,
                        float* __restrict__ trace,
                        const float* __restrict__ tp1w, const float* __restrict__ tp1b,
                        const float* __restrict__ tp2w, const float* __restrict__ tp2b,
                        float* __restrict__ act, half_t* __restrict__ Ah16, int t){
  const int b = blockIdx.x, tid = threadIdx.x;   // 512 threads
  __shared__ float vals[D_MODEL];
  __shared__ float red[512];
  // phase 1: GLU for c = tid, tid+512
#pragma unroll
  for (int q = 0; q < 2; q++){
    int c = tid + q*512;
    float a = bias2[c], gg = bias2[c+1024];
#pragma unroll
    for (int z = 0; z < SYNZ; z++){
      const float* sp = synpart + (size_t)z*BB*2048 + (size_t)b*2048;
      a  += sp[c];
      gg += sp[c+1024];
    }
    vals[c] = a * sigmoidf_(gg);
  }
  __syncthreads();
  // phase 2: LN over 1024 elems (each thread owns 2)
  float v0 = vals[tid], v1 = vals[tid+512];
  float mean = bsumN<512>(v0 + v1, red) * (1.f/1024.f);
  float d0 = v0 - mean, d1 = v1 - mean;
  float var = bsumN<512>(d0*d0 + d1*d1, red) * (1.f/1024.f);
  float inv = 1.f / sqrtf(var + 1e-5f);
  float* slot = trace + (size_t)b*(TRACE_SLOTS*D_MODEL) + (size_t)(MEMN+t)*D_MODEL;
  {
    float w0 = d0*inv*g[tid] + bta[tid];
    float w1 = d1*inv*g[tid+512] + bta[tid+512];
    slot[tid] = w0;       vals[tid] = w0;
    slot[tid+512] = w1;   vals[tid+512] = w1;
  }
  __syncthreads();
  // phase 3: neuron, two explicit sequential sections (register reuse, no spill)
  dev_neuron1(b, tid,       vals, trace, tp1w, tp1b, tp2w, tp2b, act, Ah16, t);
  dev_neuron1(b, tid + 512, vals, trace, tp1w, tp1b, tp2w, tp2b, act, Ah16, t);
}

// standalone wrappers (prologue/epilogue)
__global__ void k_gemmq(const float* __restrict__ act,
                        const float* __restrict__ r_a, const int2* __restrict__ pairsA,
                        const float* __restrict__ aaIn, float* __restrict__ aaOut,
                        const half_t* __restrict__ Wh, float* __restrict__ qpart, int t){
  __shared__ float AsF[4*32];
  dev_gemmq(blockIdx.x, blockIdx.y, blockIdx.z, threadIdx.x, AsF,
            act, r_a, pairsA, aaIn, aaOut, Wh, qpart, t);
}

__global__ __launch_bounds__(128)
void k_attn(const float* __restrict__ qpart, const float* __restrict__ bqf,
            const float* __restrict__ Km, const float* __restrict__ Vm,
            float* __restrict__ o, half_t* __restrict__ Ah16){
  __shared__ float sm[264];
  dev_attn(blockIdx.x, threadIdx.x, sm, sm + 64, sm + 136, qpart, bqf, Km, Vm, o, Ah16);
}

__global__ __launch_bounds__(256)
void k_bigemm2h(const half_t* __restrict__ Ah, const half_t* __restrict__ Wh,
                float* __restrict__ part){
  __shared__ half_t AsBuf[2*8192];
  __shared__ half_t WsBuf[2*4224];
  dev_bigemm(blockIdx.x, blockIdx.y, threadIdx.x, AsBuf, WsBuf, Ah, Wh, part);
}

__global__ __launch_bounds__(128)
void k_out128(const float* __restrict__ part, const float* __restrict__ outb,
              float* __restrict__ dout, int t){
  __shared__ float sm[NCLS + 128];
  dev_out128(blockIdx.x, threadIdx.x, sm, sm + NCLS, part, outb, dout, t);
}

__global__ void k_syncO(const float* __restrict__ act, const float* __restrict__ rv,
                        const int2* __restrict__ pairs, float* __restrict__ ao,
                        half_t* __restrict__ syncv, int t){
  int p = blockIdx.x*256 + threadIdx.x;
  if (p >= SO_SZ) return;
  int b = blockIdx.y;
  int2 ij = pairs[p];
  const float* ab = act + (size_t)b*D_MODEL;
  float r = rv[p];
  size_t idx = (size_t)b*SO_SZ + p;
  float a = fmaf(r, ao[idx], ab[ij.x]*ab[ij.y]);
  ao[idx] = a;
  float bb = 1.f;
  for (int i = 0; i <= t; i++) bb = fmaf(r, bb, 1.f);
  syncv[idx] = (half_t)(a / sqrtf(bb));
}

// ---- fused syn GEMM fp32 fallback ----
__global__ void k_gemm2srcZ(const float* __restrict__ A1, const float* __restrict__ A2,
                            const float* __restrict__ W1, const float* __restrict__ W2,
                            float* __restrict__ outp){
  constexpr int MB = 8, KC = 32;
  const int tid = threadIdx.x;
  const int col = blockIdx.x*256 + tid;
  const int row0 = blockIdx.y*MB;
  const int z = blockIdx.z;
  __shared__ float As[MB][KC];
  float acc[MB];
#pragma unroll
  for (int r = 0; r < MB; r++) acc[r] = 0.f;
  for (int kk = z*256; kk < z*256 + 256; kk += KC){
    __syncthreads();
    for (int idx = tid; idx < MB*KC; idx += 256){
      int r = idx / KC, k = idx % KC;
      int kg = kk + k;
      As[r][k] = (kg < D_IN) ? A1[(size_t)(row0+r)*D_IN + kg]
                             : A2[(size_t)(row0+r)*D_MODEL + kg - D_IN];
    }
    __syncthreads();
    const float* Wp = (kk < D_IN) ? W1 : W2;
#pragma unroll
    for (int k = 0; k < KC; k++){
      float w = Wp[(size_t)(kk+k)*2048 + col];
#pragma unroll
      for (int r = 0; r < MB; r++) acc[r] = fmaf(As[r][k], w, acc[r]);
    }
  }
#pragma unroll
  for (int r = 0; r < MB; r++)
    outp[(size_t)z*BB*2048 + (size_t)(row0+r)*2048 + col] = acc[r];
}

// ---------------- LayerNorm (setup), fp32 in -> fp16 out ----------------
__global__ void k_ln_h(const float* __restrict__ X, const float* __restrict__ g,
                       const float* __restrict__ bta, half_t* __restrict__ Y, int D){
  const int row = blockIdx.x, tid = threadIdx.x;
  __shared__ float red[256];
  const float* xr = X + (size_t)row*D;
  float s = 0.f;
  for (int c = tid; c < D; c += 256) s += xr[c];
  float mean = bsumN<256>(s, red) / (float)D;
  float s2 = 0.f;
  for (int c = tid; c < D; c += 256){ float d = xr[c]-mean; s2 += d*d; }
  float var = bsumN<256>(s2, red) / (float)D;
  float inv = 1.f / sqrtf(var + 1e-5f);
  half_t* yr = Y + (size_t)row*D;
  for (int c = tid; c < D; c += 256) yr[c] = (half_t)((xr[c]-mean)*inv*g[c] + bta[c]);
}

// ---------------- launch ----------------
extern "C" void kernel_launch(void* const* d_in, const int* in_sizes, int n_in,
                              void* d_out, int out_size, void* d_ws, size_t ws_size,
                              hipStream_t stream){
  const int*   x           = (const int*)  d_in[0];
  const float* emb         = (const float*)d_in[1];
  const float* kv_w        = (const float*)d_in[2];
  const float* kv_b        = (const float*)d_in[3];
  const float* kv_ln_g     = (const float*)d_in[4];
  const float* kv_ln_b     = (const float*)d_in[5];
  const float* q_w         = (const float*)d_in[6];
  const float* q_b         = (const float*)d_in[7];
  const float* in_proj_w   = (const float*)d_in[8];
  const float* in_proj_b   = (const float*)d_in[9];
  const float* out_proj_w  = (const float*)d_in[10];
  const float* out_proj_b  = (const float*)d_in[11];
  const float* syn_w       = (const float*)d_in[12];
  const float* syn_b       = (const float*)d_in[13];
  const float* syn_ln_g    = (const float*)d_in[14];
  const float* syn_ln_b    = (const float*)d_in[15];
  const float* tp1_w       = (const float*)d_in[16];
  const float* tp1_b       = (const float*)d_in[17];
  const float* tp2_w       = (const float*)d_in[18];
  const float* tp2_b       = (const float*)d_in[19];
  const float* start_act   = (const float*)d_in[20];
  const float* start_trace = (const float*)d_in[21];
  const float* decay_action= (const float*)d_in[22];
  const float* decay_out   = (const float*)d_in[23];
  const float* out_w       = (const float*)d_in[24];
  const float* out_b       = (const float*)d_in[25];
  float* dout = (float*)d_out;

  // ---- workspace layout (R12-identical) ----
  float* w = (float*)d_ws;
  size_t off = 0;
  auto alloc = [&](size_t n){ n = (n + 3) & ~(size_t)3; float* p = w + off; off += n; return p; };
  float* region0 = alloc((size_t)BGKS*128*NPART);
  float* region1 = alloc((size_t)ROWS*D_IN);
  float* Kmat    = alloc((size_t)ROWS*D_IN);
  float* Vmat    = alloc((size_t)ROWS*D_IN);
  float* trace   = alloc((size_t)BB*TRACE_SLOTS*D_MODEL);
  half_t* sync_oh= (half_t*)alloc((size_t)BB*SO_SZ/2);
  float* a_aP    = alloc((size_t)2*BB*SA_SZ);
  float* act     = alloc((size_t)BB*D_MODEL);
  float* qpart   = alloc((size_t)4*BB*D_IN);
  float* obuf    = alloc((size_t)BB*D_IN);
  float* qfwPad  = alloc((size_t)QPAD*D_IN);
  float* Wf2     = alloc((size_t)D_IN*2048);
  float* bqf     = alloc(D_IN);
  float* bias2   = alloc(2048);
  float* colpart = alloc((size_t)16*2048);
  float* r_a     = alloc(SA_SZ);
  float* r_o     = alloc(SO_SZ);
  int2*  pairsA  = (int2*)alloc(2*SA_SZ);
  int2*  pairsO  = (int2*)alloc(2*SO_SZ);
  half_t* embh   = (half_t*)alloc((size_t)VOCAB*TED/2);
  half_t* kvwh   = (half_t*)alloc((size_t)TED*D_IN/2);
  half_t* Wkh    = (half_t*)alloc((size_t)D_IN*D_IN/2);
  half_t* Wvh    = (half_t*)alloc((size_t)D_IN*D_IN/2);
  half_t* Wqh    = (half_t*)alloc((size_t)D_IN*D_IN/2);
  half_t* oph    = (half_t*)alloc((size_t)D_IN*D_IN/2);
  half_t* synth  = (half_t*)alloc((size_t)D_IN*2048/2);
  half_t* qwh    = (half_t*)alloc((size_t)QPAD*D_IN/2);
  half_t* qfwh   = (half_t*)alloc((size_t)SA_SZ*D_IN/2);
  half_t* Wh     = (half_t*)alloc(((size_t)SO_SZ*WHLD)/2);
  half_t* Ah16   = (half_t*)alloc((size_t)BB*1536/2);
  half_t* Wsynh  = (half_t*)alloc((size_t)1536*2048/2);
  const bool use_syn16 = (off * sizeof(float) <= ws_size);

  half_t* embx_h = (half_t*)region0;
  half_t* kvh    = (half_t*)region0;
  float* part    = region0;
  float* synpart = region0;
  float* kvbuf = region1;
  float* a_o   = region1;

  dim3 blk(256);

  // ---- setup ----
  k_convall<<<(CV7+255)/256, blk, 0, stream>>>(emb, kv_w, in_proj_w, out_proj_w, syn_w, q_w,
                                               embh, kvwh, Wkh, Wvh, Wqh, oph, synth, qwh);
  k_embed_h<<<(ROWS*(TED/8)+255)/256, blk, 0, stream>>>(x, embh, embx_h);
  k_pgemm<<<dim3(8, ROWS/128), blk, 0, stream>>>(embx_h, TED, kvwh, D_IN, kv_b, kvbuf, D_IN, TED/64);
  k_ln_h<<<ROWS, blk, 0, stream>>>(kvbuf, kv_ln_g, kv_ln_b, kvh, D_IN);
  k_pgemm<<<dim3(8, ROWS/128), blk, 0, stream>>>(kvh, D_IN, Wkh, D_IN, in_proj_b+512,  Kmat, D_IN, D_IN/64);
  k_pgemm<<<dim3(8, ROWS/128), blk, 0, stream>>>(kvh, D_IN, Wvh, D_IN, in_proj_b+1024, Vmat, D_IN, D_IN/64);
  k_pgemm<<<dim3(8, QPAD/128), blk, 0, stream>>>(qwh, D_IN, Wqh, D_IN, nullptr, qfwPad, D_IN, D_IN/64);
  k_pgemm<<<dim3(32, D_IN/128), blk, 0, stream>>>(oph, D_IN, synth, 2048, nullptr, Wf2, 2048, D_IN/64);
  k_conv<<<(SA_SZ*D_IN+255)/256, blk, 0, stream>>>(qfwPad, qfwh, SA_SZ*D_IN);
  k_colsumP<<<dim3(2, 16), blk, 0, stream>>>(q_b, in_proj_w, 1536, colpart, D_IN);
  k_colsumR<<<2, blk, 0, stream>>>(colpart, in_proj_b, bqf, D_IN);
  k_colsumP<<<dim3(8, 16), blk, 0, stream>>>(out_proj_b, syn_w, 2048, colpart, 2048);
  k_colsumR<<<8, blk, 0, stream>>>(colpart, syn_b, bias2, 2048);
  k_convw<<<(SO_SZ*WCHUNKS+255)/256, blk, 0, stream>>>(out_w, Wh);
  if (use_syn16)
    k_convsyn<<<(1536*2048+255)/256, blk, 0, stream>>>(Wf2, syn_w, Wsynh);
  k_init_pairs<<<(SA_SZ+255)/256, blk, 0, stream>>>(N_SA, SA_SZ, decay_action, pairsA, r_a);
  k_init_pairs<<<(SO_SZ+255)/256, blk, 0, stream>>>(N_SO, SO_SZ, decay_out,    pairsO, r_o);
  k_init_act<<<(BB*D_MODEL+255)/256, blk, 0, stream>>>(start_act, act, Ah16);
  k_zero<<<(2*BB*SA_SZ+255)/256, blk, 0, stream>>>(a_aP, 2*BB*SA_SZ);
  k_init_trace<<<(BB*MEMN*D_MODEL+255)/256, blk, 0, stream>>>(start_trace, trace);
  k_init_ao<<<dim3((SO_SZ+255)/256, BB), blk, 0, stream>>>(start_act, pairsO, a_o);

  // ---- recurrence (R12 depth-1 structure; tail merged into one 512-thread kernel) ----
  auto launch_syn = [&](){
    if (use_syn16)
      k_syn16<<<dim3(32, SYNZ), blk, 0, stream>>>(Ah16, Wsynh, synpart);
    else
      k_gemm2srcZ<<<dim3(8, 16, SYNZ), blk, 0, stream>>>(obuf, act, Wf2, syn_w, synpart);
  };
  auto launch_tail = [&](int t){
    k_tail2<<<BB, 512, 0, stream>>>(synpart, bias2, syn_ln_g, syn_ln_b, trace,
                                    tp1_w, tp1_b, tp2_w, tp2_b, act, Ah16, t);
  };

  // prologue t = 0
  k_gemmq<<<dim3(2, 32, 4), blk, 0, stream>>>(act, r_a, pairsA,
      a_aP, a_aP + (size_t)BB*SA_SZ, qfwh, qpart, 0);
  k_attn<<<NB_ATTN, 128, 0, stream>>>(qpart, bqf, Kmat, Vmat, obuf, Ah16);
  launch_syn();
  launch_tail(0);

  for (int t = 1; t < NITER; t++){
    float* aaIn  = a_aP + (size_t)(t & 1)*BB*SA_SZ;
    float* aaOut = a_aP + (size_t)((t+1) & 1)*BB*SA_SZ;
    k_syncO<<<dim3((SO_SZ+255)/256, BB), blk, 0, stream>>>(act, r_o, pairsO, a_o, sync_oh, t-1);
    k_AB1<<<NB_BIG + NB_Q, blk, 0, stream>>>(sync_oh, Wh, part,
        act, r_a, pairsA, aaIn, aaOut, qfwh, qpart, t);
    k_AB2<<<NB_ATTN + BB, 128, 0, stream>>>(qpart, bqf, Kmat, Vmat, obuf, Ah16,
        part, out_b, dout, t-1);
    launch_syn();
    launch_tail(t);
  }

  // epilogue t = 15 output branch
  k_syncO<<<dim3((SO_SZ+255)/256, BB), blk, 0, stream>>>(act, r_o, pairsO, a_o, sync_oh, NITER-1);
  k_bigemm2h<<<dim3(31, BGKS), blk, 0, stream>>>(sync_oh, Wh, part);
  k_out128<<<BB, 128, 0, stream>>>(part, out_b, dout, NITER-1);
}

// Round 15
// 2623.815 us; speedup vs baseline: 4.1781x; 4.1781x over previous
//
#include <hip/hip_runtime.h>
#include <math.h>

#define BB 128
#define SS 72
#define NITER 16
#define D_IN 512
#define D_MODEL 1024
#define MEMN 25
#define HEADS 8
#define DHH 64
#define N_SO 256
#define N_SA 64
#define SA_SZ 2080
#define SO_SZ 32896
#define NCLS 1968
#define TED 128
#define VOCAB 32
#define ROWS (BB*SS)
#define TRACE_SLOTS (MEMN + NITER)   /* 41 */
#define QPAD 2176                    /* SA_SZ padded to 17*128 */

/* big-GEMM (sync_o @ out_w) tiling */
#define BGN 64
#define BGKS 16
#define BGKLEN 2056
#define BGSTEPS 33
#define NPART 1984
#define WHLD 1984
#define WCHUNKS 124
#define SYNZ 6
#define NB_BIG 496                   /* 31*16 bigemm blocks in AB1 */
#define NB_Q 256                     /* 2*32*4 gemmq blocks in AB1 */
#define NB_ATTN 1024                 /* BB*HEADS attn blocks in AB2 */

typedef _Float16 half_t;
typedef _Float16 half8 __attribute__((ext_vector_type(8)));
typedef float f32x4v __attribute__((ext_vector_type(4)));

__device__ __forceinline__ float sigmoidf_(float x){ return 1.f/(1.f+expf(-x)); }

template<int NT>
__device__ __forceinline__ float bsumN(float v, float* red){
  int tid = threadIdx.x; red[tid] = v; __syncthreads();
#pragma unroll
  for (int s = NT/2; s > 0; s >>= 1){ if (tid < s) red[tid] += red[tid+s]; __syncthreads(); }
  float r = red[0]; __syncthreads(); return r;
}

__device__ __forceinline__ long triu_off(int n, int i){
  return (long)i*n - ((long)i*(i-1))/2;
}

__device__ __forceinline__ int swzA(int b){ return b ^ (((b>>9)&1)<<5); }

// ---------------- setup kernels ----------------
__global__ void k_conv(const float* __restrict__ src, half_t* __restrict__ dst, int n){
  int gid = blockIdx.x*256 + threadIdx.x;
  if (gid < n) dst[gid] = (half_t)src[gid];
}

// merged fp32->fp16 weight conversions
#define CV0 (VOCAB*TED)
#define CV1 (CV0 + TED*D_IN)
#define CV2 (CV1 + D_IN*D_IN)
#define CV3 (CV2 + D_IN*D_IN)
#define CV4 (CV3 + D_IN*D_IN)
#define CV5 (CV4 + D_IN*D_IN)
#define CV6 (CV5 + D_IN*2048)
#define CV7 (CV6 + QPAD*D_IN)
__global__ void k_convall(const float* __restrict__ emb, const float* __restrict__ kv_w,
                          const float* __restrict__ in_proj_w,
                          const float* __restrict__ out_proj_w,
                          const float* __restrict__ syn_w, const float* __restrict__ q_w,
                          half_t* __restrict__ embh, half_t* __restrict__ kvwh,
                          half_t* __restrict__ Wkh, half_t* __restrict__ Wvh,
                          half_t* __restrict__ Wqh, half_t* __restrict__ oph,
                          half_t* __restrict__ synth, half_t* __restrict__ qwh){
  int gid = blockIdx.x*256 + threadIdx.x;
  if (gid < CV0){ embh[gid] = (half_t)emb[gid]; return; }
  if (gid < CV1){ int i = gid - CV0; kvwh[i] = (half_t)kv_w[i]; return; }
  if (gid < CV2){ int i = gid - CV1; int r = i >> 9, c = i & 511;
                  Wkh[i] = (half_t)in_proj_w[(size_t)r*1536 + 512 + c]; return; }
  if (gid < CV3){ int i = gid - CV2; int r = i >> 9, c = i & 511;
                  Wvh[i] = (half_t)in_proj_w[(size_t)r*1536 + 1024 + c]; return; }
  if (gid < CV4){ int i = gid - CV3; int r = i >> 9, c = i & 511;
                  Wqh[i] = (half_t)in_proj_w[(size_t)r*1536 + c]; return; }
  if (gid < CV5){ int i = gid - CV4; oph[i] = (half_t)out_proj_w[i]; return; }
  if (gid < CV6){ int i = gid - CV5; synth[i] = (half_t)syn_w[i]; return; }
  if (gid < CV7){ int i = gid - CV6; int r = i >> 9;
                  qwh[i] = (r < SA_SZ) ? (half_t)q_w[i] : (half_t)0.f; return; }
}

__global__ void k_convsyn(const float* __restrict__ Wf2, const float* __restrict__ syn_w,
                          half_t* __restrict__ Wsynh){
  int gid = blockIdx.x*256 + threadIdx.x;
  if (gid >= 1536*2048) return;
  Wsynh[gid] = (half_t)((gid < 512*2048) ? Wf2[gid] : syn_w[gid]);
}

__global__ void k_embed_h(const int* __restrict__ x, const half_t* __restrict__ embh,
                          half_t* __restrict__ out){
  int gid = blockIdx.x*256 + threadIdx.x;
  if (gid >= ROWS*(TED/8)) return;
  int row = gid >> 4, c0 = (gid & 15)*8;
  *(half8*)(out + (size_t)row*TED + c0) = *(const half8*)(embh + (size_t)x[row]*TED + c0);
}

__global__ void k_init_pairs(int n, int npairs, const float* __restrict__ decay,
                             int2* __restrict__ pairs, float* __restrict__ rv){
  int p = blockIdx.x*256 + threadIdx.x;
  if (p >= npairs) return;
  double nn = (double)n;
  double disc = (2.0*nn+1.0)*(2.0*nn+1.0) - 8.0*(double)p;
  int i = (int)floor(((2.0*nn+1.0) - sqrt(disc))*0.5);
  if (i < 0) i = 0; if (i > n-1) i = n-1;
  while (i+1 < n && triu_off(n, i+1) <= (long)p) i++;
  while (i > 0 && triu_off(n, i) > (long)p) i--;
  int j = i + (int)((long)p - triu_off(n, i));
  pairs[p] = make_int2(i, j);
  float dc = decay[p]; dc = fminf(fmaxf(dc, 0.f), 15.f);
  rv[p] = expf(-dc);
}

__global__ void k_init_act(const float* __restrict__ sa, float* __restrict__ act,
                           half_t* __restrict__ Ah16){
  int gid = blockIdx.x*256 + threadIdx.x;
  if (gid >= BB*D_MODEL) return;
  int b = gid >> 10, d = gid & 1023;
  float v = sa[d];
  act[gid] = v;
  Ah16[(size_t)b*1536 + 512 + d] = (half_t)v;
}

__global__ void k_zero(float* __restrict__ p, int n){
  int gid = blockIdx.x*256 + threadIdx.x;
  if (gid < n) p[gid] = 0.f;
}

__global__ void k_init_trace(const float* __restrict__ st, float* __restrict__ trace){
  int gid = blockIdx.x*256 + threadIdx.x;
  if (gid >= BB*MEMN*D_MODEL) return;
  int d = gid & 1023;
  int m = (gid >> 10) % MEMN;
  int b = (gid >> 10) / MEMN;
  trace[(size_t)b*TRACE_SLOTS*D_MODEL + (size_t)m*D_MODEL + d] = st[d*MEMN + m];
}

__global__ void k_init_ao(const float* __restrict__ sa, const int2* __restrict__ pairs,
                          float* __restrict__ ao){
  int p = blockIdx.x*256 + threadIdx.x;
  if (p >= SO_SZ) return;
  int b = blockIdx.y;
  int2 ij = pairs[p];
  ao[(size_t)b*SO_SZ + p] = sa[ij.x]*sa[ij.y];
}

__global__ void k_convw(const float* __restrict__ W, half_t* __restrict__ Wh){
  int gid = blockIdx.x*256 + threadIdx.x;
  if (gid >= SO_SZ*WCHUNKS) return;
  int row = gid / WCHUNKS, ch = gid - row*WCHUNKS;
  int c0 = ch*16;
  half_t* dst = Wh + (size_t)row*WHLD + c0;
  if (ch < 123){
    const float4* src = (const float4*)(W + (size_t)row*NCLS + c0);
    float4 f0 = src[0], f1 = src[1], f2 = src[2], f3 = src[3];
    half8 h0, h1;
    h0[0]=(half_t)f0.x; h0[1]=(half_t)f0.y; h0[2]=(half_t)f0.z; h0[3]=(half_t)f0.w;
    h0[4]=(half_t)f1.x; h0[5]=(half_t)f1.y; h0[6]=(half_t)f1.z; h0[7]=(half_t)f1.w;
    h1[0]=(half_t)f2.x; h1[1]=(half_t)f2.y; h1[2]=(half_t)f2.z; h1[3]=(half_t)f2.w;
    h1[4]=(half_t)f3.x; h1[5]=(half_t)f3.y; h1[6]=(half_t)f3.z; h1[7]=(half_t)f3.w;
    *(half8*)dst = h0; *(half8*)(dst+8) = h1;
  } else {
    half8 zz;
#pragma unroll
    for (int j = 0; j < 8; j++) zz[j] = (half_t)0.f;
    *(half8*)dst = zz; *(half8*)(dst+8) = zz;
  }
}

__global__ void k_colsumP(const float* __restrict__ vec, const float* __restrict__ W,
                          int ldw, float* __restrict__ part, int N){
  int col = blockIdx.x*256 + threadIdx.x;
  int kz = blockIdx.y;
  if (col >= N) return;
  float s = 0.f;
#pragma unroll
  for (int k = kz*32; k < kz*32 + 32; k++)
    s = fmaf(vec[k], W[(size_t)k*ldw + col], s);
  part[(size_t)kz*N + col] = s;
}

__global__ void k_colsumR(const float* __restrict__ part, const float* __restrict__ addb,
                          float* __restrict__ out, int N){
  int col = blockIdx.x*256 + threadIdx.x;
  if (col >= N) return;
  float s = addb[col];
#pragma unroll
  for (int z = 0; z < 16; z++) s += part[(size_t)z*N + col];
  out[col] = s;
}

// ---- fp16 MFMA GEMM (generalized, setup): C = Ah @ Wh16 + bias ----
__global__ __launch_bounds__(256)
void k_pgemm(const half_t* __restrict__ Ah, int ldah,
             const half_t* __restrict__ Wh16, int ldw, const float* __restrict__ bias,
             float* __restrict__ C, int ldc, int ksteps){
  __shared__ half_t As[2][128*64];
  __shared__ half_t Ws[2][64*66];
  const int tid = threadIdx.x;
  const int nb0 = blockIdx.x * 64;
  const int row0 = blockIdx.y * 128;
  const int l = tid & 63, wv = tid >> 6;
  const int mw = (wv >> 1) * 64, nw = (wv & 1) * 32;
  const int c = l & 15, g = l >> 4;

  f32x4v acc[4][2];
#pragma unroll
  for (int i = 0; i < 4; i++)
#pragma unroll
    for (int j2 = 0; j2 < 2; j2++)
#pragma unroll
      for (int r = 0; r < 4; r++) acc[i][j2][r] = 0.f;

  auto stage = [&](int s, int buf){
#pragma unroll
    for (int it = 0; it < 4; it++){
      int ch = tid + it*256;
      int m = ch >> 3, kl = (ch & 7)*8;
      half8 v = *(const half8*)(Ah + (size_t)(row0+m)*ldah + s*64 + kl);
      *(half8*)((char*)(&As[buf][0]) + swzA(ch*16)) = v;
    }
    {
      int k = tid >> 2, cs = (tid & 3) * 16;
      const half_t* wr = Wh16 + (size_t)(s*64 + k) * ldw + nb0 + cs;
      char* dst = (char*)(&Ws[buf][0]) + (size_t)(k*66 + cs) * 2;
      union { half8 v; unsigned int u[4]; } p0, p1;
      p0.v = *(const half8*)wr; p1.v = *(const half8*)(wr + 8);
#pragma unroll
      for (int q = 0; q < 4; q++){
        ((unsigned int*)dst)[q]        = p0.u[q];
        ((unsigned int*)(dst + 16))[q] = p1.u[q];
      }
    }
  };

  stage(0, 0);
  __syncthreads();
  for (int s = 0; s < ksteps; s++){
    int buf = s & 1;
    if (s + 1 < ksteps) stage(s+1, buf^1);
#pragma unroll
    for (int h = 0; h < 2; h++){
      half8 a8[4];
#pragma unroll
      for (int mb = 0; mb < 4; mb++)
        a8[mb] = *(const half8*)((const char*)(&As[buf][0]) +
                   swzA(((mw + mb*16 + c)*64 + h*32 + g*8)*2));
#pragma unroll
      for (int nb = 0; nb < 2; nb++){
        half8 b8;
        const half_t* wp = &Ws[buf][(h*32 + g*8)*66 + nw + nb*16 + c];
#pragma unroll
        for (int j = 0; j < 8; j++) b8[j] = wp[j*66];
#pragma unroll
        for (int mb = 0; mb < 4; mb++)
          acc[mb][nb] = __builtin_amdgcn_mfma_f32_16x16x32_f16(a8[mb], b8, acc[mb][nb], 0, 0, 0);
      }
    }
    __syncthreads();
  }
#pragma unroll
  for (int mb = 0; mb < 4; mb++)
#pragma unroll
    for (int nb = 0; nb < 2; nb++){
      int m = mw + mb*16 + g*4;
      int n = nb0 + nw + nb*16 + c;
      float bv = bias ? bias[n] : 0.f;
#pragma unroll
      for (int r = 0; r < 4; r++)
        C[(size_t)(row0 + m + r) * ldc + n] = acc[mb][nb][r] + bv;
    }
}

// ---- syn fp16 MFMA GEMM ----
__global__ __launch_bounds__(256)
void k_syn16(const half_t* __restrict__ Ah, const half_t* __restrict__ Wh16,
             float* __restrict__ outp){
  __shared__ half_t As[2][128*64];
  __shared__ half_t Ws[2][64*66];
  const int tid = threadIdx.x;
  const int nb0 = blockIdx.x * 64;
  const int z = blockIdx.y;
  const int l = tid & 63, wv = tid >> 6;
  const int mw = (wv >> 1) * 64, nw = (wv & 1) * 32;
  const int c = l & 15, g = l >> 4;
  const int kbase = z * 256;

  f32x4v acc[4][2];
#pragma unroll
  for (int i = 0; i < 4; i++)
#pragma unroll
    for (int j2 = 0; j2 < 2; j2++)
#pragma unroll
      for (int r = 0; r < 4; r++) acc[i][j2][r] = 0.f;

  auto stage = [&](int s, int buf){
#pragma unroll
    for (int it = 0; it < 4; it++){
      int ch = tid + it*256;
      int m = ch >> 3, kl = (ch & 7)*8;
      half8 v = *(const half8*)(Ah + (size_t)m*1536 + kbase + s*64 + kl);
      *(half8*)((char*)(&As[buf][0]) + swzA(ch*16)) = v;
    }
    {
      int k = tid >> 2, cs = (tid & 3) * 16;
      const half_t* wr = Wh16 + (size_t)(kbase + s*64 + k) * 2048 + nb0 + cs;
      char* dst = (char*)(&Ws[buf][0]) + (size_t)(k*66 + cs) * 2;
      union { half8 v; unsigned int u[4]; } p0, p1;
      p0.v = *(const half8*)wr; p1.v = *(const half8*)(wr + 8);
#pragma unroll
      for (int q = 0; q < 4; q++){
        ((unsigned int*)dst)[q]        = p0.u[q];
        ((unsigned int*)(dst + 16))[q] = p1.u[q];
      }
    }
  };

  stage(0, 0);
  __syncthreads();
  for (int s = 0; s < 4; s++){
    int buf = s & 1;
    if (s + 1 < 4) stage(s+1, buf^1);
#pragma unroll
    for (int h = 0; h < 2; h++){
      half8 a8[4];
#pragma unroll
      for (int mb = 0; mb < 4; mb++)
        a8[mb] = *(const half8*)((const char*)(&As[buf][0]) +
                   swzA(((mw + mb*16 + c)*64 + h*32 + g*8)*2));
#pragma unroll
      for (int nb = 0; nb < 2; nb++){
        half8 b8;
        const half_t* wp = &Ws[buf][(h*32 + g*8)*66 + nw + nb*16 + c];
#pragma unroll
        for (int j = 0; j < 8; j++) b8[j] = wp[j*66];
#pragma unroll
        for (int mb = 0; mb < 4; mb++)
          acc[mb][nb] = __builtin_amdgcn_mfma_f32_16x16x32_f16(a8[mb], b8, acc[mb][nb], 0, 0, 0);
      }
    }
    __syncthreads();
  }
  float* pz = outp + (size_t)z * BB * 2048;
#pragma unroll
  for (int mb = 0; mb < 4; mb++)
#pragma unroll
    for (int nb = 0; nb < 2; nb++){
      int m = mw + mb*16 + g*4;
      int n = nb0 + nw + nb*16 + c;
#pragma unroll
      for (int r = 0; r < 4; r++)
        pz[(size_t)(m + r) * 2048 + n] = acc[mb][nb][r];
    }
}

// ================= device bodies =================

__device__ __forceinline__ void dev_bigemm(int bx, int z, int tid,
    half_t* AsBuf, half_t* WsBuf,
    const half_t* __restrict__ Ah, const half_t* __restrict__ Wh,
    float* __restrict__ part){
  const int nb0 = bx * BGN;
  const int l = tid & 63, wv = tid >> 6;
  const int mw = (wv >> 1) * 64, nw = (wv & 1) * 32;
  const int c = l & 15, g = l >> 4;
  const int k0 = z * BGKLEN;

  f32x4v acc[4][2];
#pragma unroll
  for (int i = 0; i < 4; i++)
#pragma unroll
    for (int j2 = 0; j2 < 2; j2++)
#pragma unroll
      for (int r = 0; r < 4; r++) acc[i][j2][r] = 0.f;

  auto stage = [&](int s, int buf){
    const int kv = min(64, BGKLEN - s*64);
    half_t* As = AsBuf + buf*8192;
    half_t* Ws = WsBuf + buf*4224;
#pragma unroll
    for (int it = 0; it < 4; it++){
      int ch = tid + it*256;
      int m = ch >> 3, kg = ch & 7, kl = kg*8;
      half8 v;
      if (kl < kv) v = *(const half8*)(Ah + (size_t)m*SO_SZ + k0 + s*64 + kl);
      else {
#pragma unroll
        for (int j = 0; j < 8; j++) v[j] = (half_t)0.f;
      }
      *(half8*)((char*)As + swzA(ch*16)) = v;
    }
    {
      int k = tid >> 2, cs = (tid & 3) * 16;
      const half_t* wr = Wh + (size_t)(k0 + s*64 + k) * WHLD + nb0 + cs;
      char* dst = (char*)Ws + (size_t)(k*66 + cs) * 2;
      union { half8 v; unsigned int u[4]; } p0, p1;
      if (k < kv){ p0.v = *(const half8*)wr; p1.v = *(const half8*)(wr + 8); }
      else {
#pragma unroll
        for (int j = 0; j < 8; j++){ p0.v[j] = (half_t)0.f; p1.v[j] = (half_t)0.f; }
      }
#pragma unroll
      for (int q = 0; q < 4; q++){
        ((unsigned int*)dst)[q]        = p0.u[q];
        ((unsigned int*)(dst + 16))[q] = p1.u[q];
      }
    }
  };

  stage(0, 0);
  __syncthreads();
  for (int s = 0; s < BGSTEPS; s++){
    int buf = s & 1;
    if (s + 1 < BGSTEPS) stage(s+1, buf^1);
    half_t* As = AsBuf + buf*8192;
    half_t* Ws = WsBuf + buf*4224;
#pragma unroll
    for (int h = 0; h < 2; h++){
      half8 a8[4];
#pragma unroll
      for (int mb = 0; mb < 4; mb++)
        a8[mb] = *(const half8*)((const char*)As +
                   swzA(((mw + mb*16 + c)*64 + h*32 + g*8)*2));
#pragma unroll
      for (int nb = 0; nb < 2; nb++){
        half8 b8;
        const half_t* wp = Ws + (h*32 + g*8)*66 + nw + nb*16 + c;
#pragma unroll
        for (int j = 0; j < 8; j++) b8[j] = wp[j*66];
#pragma unroll
        for (int mb = 0; mb < 4; mb++)
          acc[mb][nb] = __builtin_amdgcn_mfma_f32_16x16x32_f16(a8[mb], b8, acc[mb][nb], 0, 0, 0);
      }
    }
    __syncthreads();
  }
  float* pz = part + (size_t)z * 128 * NPART;
#pragma unroll
  for (int mb = 0; mb < 4; mb++)
#pragma unroll
    for (int nb = 0; nb < 2; nb++){
      int m = mw + mb*16 + g*4;
      int n = nb0 + nw + nb*16 + c;
#pragma unroll
      for (int r = 0; r < 4; r++)
        pz[(size_t)(m + r) * NPART + n] = acc[mb][nb][r];
    }
}

__device__ __forceinline__ void dev_gemmq(int gx, int gy, int z, int tid, float* AsF,
    const float* __restrict__ act,
    const float* __restrict__ r_a, const int2* __restrict__ pairsA,
    const float* __restrict__ aaIn, float* __restrict__ aaOut,
    const half_t* __restrict__ Wh, float* __restrict__ qpart, int t){
  constexpr int KC = 32;
  const int col = gx*256 + tid;
  const int row0 = gy*4;
  const int kstart = z*544;
  const int kend = min(SA_SZ, kstart + 544);
  const bool writer = (gx == 0);
  float acc[4] = {0.f,0.f,0.f,0.f};
  for (int kk = kstart; kk < kend; kk += KC){
    __syncthreads();
    if (tid < 4*KC){
      int r = tid >> 5, k = tid & 31;
      int p = kk + k;
      int b = row0 + r;
      int2 ij = pairsA[p];
      const float* ab = act + (size_t)b*D_MODEL + (D_MODEL - N_SA);
      float rv = r_a[p];
      size_t idx = (size_t)b*SA_SZ + p;
      float a = fmaf(rv, aaIn[idx], ab[ij.x]*ab[ij.y]);
      if (writer) aaOut[idx] = a;
      float bb = 0.f;
      for (int i = 0; i <= t; i++) bb = fmaf(rv, bb, 1.f);
      AsF[r*KC + k] = a / sqrtf(bb);
    }
    __syncthreads();
#pragma unroll
    for (int k = 0; k < KC; k++){
      float w = (float)Wh[(size_t)(kk+k)*D_IN + col];
#pragma unroll
      for (int r = 0; r < 4; r++) acc[r] = fmaf(AsF[r*KC + k], w, acc[r]);
    }
  }
#pragma unroll
  for (int r = 0; r < 4; r++)
    qpart[(size_t)z*BB*D_IN + (size_t)(row0+r)*D_IN + col] = acc[r];
}

__device__ __forceinline__ void dev_attn(int bh, int tid,
    float* qs, float* attnv, float* red,
    const float* __restrict__ qpart, const float* __restrict__ bqf,
    const float* __restrict__ Km, const float* __restrict__ Vm,
    float* __restrict__ o, half_t* __restrict__ Ah16){
  const int b = bh >> 3, h = bh & 7;
  if (tid < DHH){
    int d = h*DHH + tid;
    float qv = bqf[d];
#pragma unroll
    for (int z = 0; z < 4; z++) qv += qpart[(size_t)z*BB*D_IN + (size_t)b*D_IN + d];
    qs[tid] = qv;
  }
  __syncthreads();
  float sc = -1e30f;
  if (tid < SS){
    const float* kp = Km + ((size_t)(b*SS+tid)*HEADS + h)*DHH;
    float d = 0.f;
#pragma unroll
    for (int i = 0; i < DHH; i++) d = fmaf(qs[i], kp[i], d);
    sc = d * 0.125f;
  }
  red[tid] = sc; __syncthreads();
  for (int s2 = 64; s2 > 0; s2 >>= 1){ if (tid < s2) red[tid] = fmaxf(red[tid], red[tid+s2]); __syncthreads(); }
  float m = red[0]; __syncthreads();
  float e = (tid < SS) ? expf(sc - m) : 0.f;
  red[tid] = e; __syncthreads();
  for (int s2 = 64; s2 > 0; s2 >>= 1){ if (tid < s2) red[tid] += red[tid+s2]; __syncthreads(); }
  float inv = 1.f / red[0]; __syncthreads();
  if (tid < SS) attnv[tid] = e * inv;
  __syncthreads();
  if (tid < DHH){
    const float* vp = Vm + ((size_t)(b*SS)*HEADS + h)*DHH + tid;
    float acc = 0.f;
    for (int s2 = 0; s2 < SS; s2++) acc = fmaf(attnv[s2], vp[(size_t)s2*D_IN], acc);
    int d = h*DHH + tid;
    o[(size_t)b*D_IN + d] = acc;
    Ah16[(size_t)b*1536 + d] = (half_t)acc;
  }
}

__device__ __forceinline__ void dev_out128(int b, int tid, float* pred, float* red,
    const float* __restrict__ part, const float* __restrict__ outb,
    float* __restrict__ dout, int t){
  float lmax = -1e30f;
  for (int c = tid; c < NCLS; c += 128){
    float s = outb[c];
    const float* pp = part + (size_t)b*NPART + c;
#pragma unroll
    for (int z = 0; z < BGKS; z++) s += pp[(size_t)z*128*NPART];
    pred[c] = s;
    dout[((size_t)b*NCLS + c)*NITER + t] = s;
    lmax = fmaxf(lmax, s);
  }
  red[tid] = lmax; __syncthreads();
  for (int s2 = 64; s2 > 0; s2 >>= 1){ if (tid < s2) red[tid] = fmaxf(red[tid], red[tid+s2]); __syncthreads(); }
  float m = red[0]; __syncthreads();
  float se = 0.f;
  for (int c = tid; c < NCLS; c += 128) se += expf(pred[c]-m);
  float Z = bsumN<128>(se, red);
  float logZ = m + logf(Z);
  float ent = 0.f;
  for (int c = tid; c < NCLS; c += 128){ float lp = pred[c]-logZ; ent += expf(lp)*lp; }
  float E = bsumN<128>(ent, red);
  if (tid == 0){
    float ne = -E * (1.f/logf((float)NCLS));
    float* cp = dout + (size_t)BB*NCLS*NITER + (size_t)b*2*NITER + t;
    cp[0]     = ne;
    cp[NITER] = 1.f - ne;
  }
}

// ================= merged + standalone kernels =================

// AB1: blocks [0,496) bigemm(t-1); blocks [496,752) gemmq(t)
__global__ __launch_bounds__(256)
void k_AB1(const half_t* __restrict__ sync_oh, const half_t* __restrict__ Wh,
           float* __restrict__ part,
           const float* __restrict__ act, const float* __restrict__ r_a,
           const int2* __restrict__ pairsA,
           const float* __restrict__ aaIn, float* __restrict__ aaOut,
           const half_t* __restrict__ qfwh, float* __restrict__ qpart, int t){
  __shared__ half_t AsBuf[2*8192];
  __shared__ half_t WsBuf[2*4224];
  int blk = blockIdx.x, tid = threadIdx.x;
  if (blk < NB_BIG){
    dev_bigemm(blk % 31, blk / 31, tid, AsBuf, WsBuf, sync_oh, Wh, part);
  } else {
    int i = blk - NB_BIG;            // 256 blocks: z(4) x gx(2) x gy(32)
    dev_gemmq((i>>5)&1, i&31, i>>6, tid, (float*)AsBuf,
              act, r_a, pairsA, aaIn, aaOut, qfwh, qpart, t);
  }
}

// AB2 (128 threads): blocks [0,1024) attn(t); blocks [1024,1152) output(t-1)
__global__ __launch_bounds__(128)
void k_AB2(const float* __restrict__ qpart, const float* __restrict__ bqf,
           const float* __restrict__ Km, const float* __restrict__ Vm,
           float* __restrict__ o, half_t* __restrict__ Ah16,
           const float* __restrict__ part, const float* __restrict__ outb,
           float* __restrict__ dout, int tprev){
  __shared__ float sm[NCLS + 128];
  int blk = blockIdx.x, tid = threadIdx.x;
  if (blk < NB_ATTN){
    dev_attn(blk, tid, sm, sm + 64, sm + 136, qpart, bqf, Km, Vm, o, Ah16);
  } else {
    dev_out128(blk - NB_ATTN, tid, sm, sm + NCLS, part, outb, dout, tprev);
  }
}

// standalone wrappers (prologue/epilogue)
__global__ void k_gemmq(const float* __restrict__ act,
                        const float* __restrict__ r_a, const int2* __restrict__ pairsA,
                        const float* __restrict__ aaIn, float* __restrict__ aaOut,
                        const half_t* __restrict__ Wh, float* __restrict__ qpart, int t){
  __shared__ float AsF[4*32];
  dev_gemmq(blockIdx.x, blockIdx.y, blockIdx.z, threadIdx.x, AsF,
            act, r_a, pairsA, aaIn, aaOut, Wh, qpart, t);
}

__global__ __launch_bounds__(128)
void k_attn(const float* __restrict__ qpart, const float* __restrict__ bqf,
            const float* __restrict__ Km, const float* __restrict__ Vm,
            float* __restrict__ o, half_t* __restrict__ Ah16){
  __shared__ float sm[264];
  dev_attn(blockIdx.x, threadIdx.x, sm, sm + 64, sm + 136, qpart, bqf, Km, Vm, o, Ah16);
}

__global__ __launch_bounds__(256)
void k_bigemm2h(const half_t* __restrict__ Ah, const half_t* __restrict__ Wh,
                float* __restrict__ part){
  __shared__ half_t AsBuf[2*8192];
  __shared__ half_t WsBuf[2*4224];
  dev_bigemm(blockIdx.x, blockIdx.y, threadIdx.x, AsBuf, WsBuf, Ah, Wh, part);
}

__global__ __launch_bounds__(128)
void k_out128(const float* __restrict__ part, const float* __restrict__ outb,
              float* __restrict__ dout, int t){
  __shared__ float sm[NCLS + 128];
  dev_out128(blockIdx.x, threadIdx.x, sm, sm + NCLS, part, outb, dout, t);
}

__global__ void k_syncO(const float* __restrict__ act, const float* __restrict__ rv,
                        const int2* __restrict__ pairs, float* __restrict__ ao,
                        half_t* __restrict__ syncv, int t){
  int p = blockIdx.x*256 + threadIdx.x;
  if (p >= SO_SZ) return;
  int b = blockIdx.y;
  int2 ij = pairs[p];
  const float* ab = act + (size_t)b*D_MODEL;
  float r = rv[p];
  size_t idx = (size_t)b*SO_SZ + p;
  float a = fmaf(r, ao[idx], ab[ij.x]*ab[ij.y]);
  ao[idx] = a;
  float bb = 1.f;
  for (int i = 0; i <= t; i++) bb = fmaf(r, bb, 1.f);
  syncv[idx] = (half_t)(a / sqrtf(bb));
}

// ---- fused syn GEMM fp32 fallback ----
__global__ void k_gemm2srcZ(const float* __restrict__ A1, const float* __restrict__ A2,
                            const float* __restrict__ W1, const float* __restrict__ W2,
                            float* __restrict__ outp){
  constexpr int MB = 8, KC = 32;
  const int tid = threadIdx.x;
  const int col = blockIdx.x*256 + tid;
  const int row0 = blockIdx.y*MB;
  const int z = blockIdx.z;
  __shared__ float As[MB][KC];
  float acc[MB];
#pragma unroll
  for (int r = 0; r < MB; r++) acc[r] = 0.f;
  for (int kk = z*256; kk < z*256 + 256; kk += KC){
    __syncthreads();
    for (int idx = tid; idx < MB*KC; idx += 256){
      int r = idx / KC, k = idx % KC;
      int kg = kk + k;
      As[r][k] = (kg < D_IN) ? A1[(size_t)(row0+r)*D_IN + kg]
                             : A2[(size_t)(row0+r)*D_MODEL + kg - D_IN];
    }
    __syncthreads();
    const float* Wp = (kk < D_IN) ? W1 : W2;
#pragma unroll
    for (int k = 0; k < KC; k++){
      float w = Wp[(size_t)(kk+k)*2048 + col];
#pragma unroll
      for (int r = 0; r < MB; r++) acc[r] = fmaf(As[r][k], w, acc[r]);
    }
  }
#pragma unroll
  for (int r = 0; r < MB; r++)
    outp[(size_t)z*BB*2048 + (size_t)(row0+r)*2048 + col] = acc[r];
}

// ---------------- LayerNorm (setup), fp32 in -> fp16 out ----------------
__global__ void k_ln_h(const float* __restrict__ X, const float* __restrict__ g,
                       const float* __restrict__ bta, half_t* __restrict__ Y, int D){
  const int row = blockIdx.x, tid = threadIdx.x;
  __shared__ float red[256];
  const float* xr = X + (size_t)row*D;
  float s = 0.f;
  for (int c = tid; c < D; c += 256) s += xr[c];
  float mean = bsumN<256>(s, red) / (float)D;
  float s2 = 0.f;
  for (int c = tid; c < D; c += 256){ float d = xr[c]-mean; s2 += d*d; }
  float var = bsumN<256>(s2, red) / (float)D;
  float inv = 1.f / sqrtf(var + 1e-5f);
  half_t* yr = Y + (size_t)row*D;
  for (int c = tid; c < D; c += 256) yr[c] = (half_t)((xr[c]-mean)*inv*g[c] + bta[c]);
}

// ---- sum 6 synpart + bias2 -> GLU -> LN -> trace slot (proven) ----
__global__ void k_glu_ln(const float* __restrict__ synpart, const float* __restrict__ bias2,
                         const float* __restrict__ g, const float* __restrict__ bta,
                         float* __restrict__ traceSlot){
  const int b = blockIdx.x, tid = threadIdx.x;
  __shared__ float vals[D_MODEL];
  __shared__ float red[256];
  for (int c = tid; c < 1024; c += 256){
    float a = bias2[c], gg = bias2[c+1024];
#pragma unroll
    for (int z = 0; z < SYNZ; z++){
      const float* sp = synpart + (size_t)z*BB*2048 + (size_t)b*2048;
      a  += sp[c];
      gg += sp[c+1024];
    }
    vals[c] = a * sigmoidf_(gg);
  }
  __syncthreads();
  float s = 0.f;
  for (int c = tid; c < 1024; c += 256) s += vals[c];
  float mean = bsumN<256>(s, red) * (1.f/1024.f);
  float s2 = 0.f;
  for (int c = tid; c < 1024; c += 256){ float d = vals[c]-mean; s2 += d*d; }
  float var = bsumN<256>(s2, red) * (1.f/1024.f);
  float inv = 1.f / sqrtf(var + 1e-5f);
  float* out = traceSlot + (size_t)b*(TRACE_SLOTS*D_MODEL);
  for (int c = tid; c < 1024; c += 256) out[c] = (vals[c]-mean)*inv*g[c] + bta[c];
}

// ---- neuron update (proven): 1 d per thread, 512 blocks ----
__global__ void k_neuron(const float* __restrict__ trace,
                         const float* __restrict__ tp1w, const float* __restrict__ tp1b,
                         const float* __restrict__ tp2w, const float* __restrict__ tp2b,
                         float* __restrict__ act, half_t* __restrict__ Ah16, int t){
  int gid = blockIdx.x*256 + threadIdx.x;
  if (gid >= BB*D_MODEL) return;
  int b = gid >> 10, d = gid & 1023;
  const float* tr = trace + (size_t)b*(TRACE_SLOTS*D_MODEL) + (size_t)(t+1)*D_MODEL + d;
  float trv[MEMN];
#pragma unroll
  for (int m = 0; m < MEMN; m++) trv[m] = tr[(size_t)m*D_MODEL];
  float o0 = tp2b[d*2+0], o1 = tp2b[d*2+1];
#pragma unroll
  for (int j = 0; j < 16; j++){
    const float* wpj = tp1w + (size_t)j*1024 + d;
    const float* wpg = tp1w + (size_t)(j+16)*1024 + d;
    float hj = tp1b[d*32 + j];
    float hg = tp1b[d*32 + j + 16];
#pragma unroll
    for (int m = 0; m < MEMN; m++){
      float tv = trv[m];
      hj = fmaf(tv, wpj[(size_t)m*32*1024], hj);
      hg = fmaf(tv, wpg[(size_t)m*32*1024], hg);
    }
    float hgv = hj * sigmoidf_(hg);
    o0 = fmaf(hgv, tp2w[(size_t)(j*2+0)*1024 + d], o0);
    o1 = fmaf(hgv, tp2w[(size_t)(j*2+1)*1024 + d], o1);
  }
  float v = o0 * sigmoidf_(o1);
  act[gid] = v;
  Ah16[(size_t)b*1536 + 512 + d] = (half_t)v;
}

// ---------------- launch ----------------
extern "C" void kernel_launch(void* const* d_in, const int* in_sizes, int n_in,
                              void* d_out, int out_size, void* d_ws, size_t ws_size,
                              hipStream_t stream){
  const int*   x           = (const int*)  d_in[0];
  const float* emb         = (const float*)d_in[1];
  const float* kv_w        = (const float*)d_in[2];
  const float* kv_b        = (const float*)d_in[3];
  const float* kv_ln_g     = (const float*)d_in[4];
  const float* kv_ln_b     = (const float*)d_in[5];
  const float* q_w         = (const float*)d_in[6];
  const float* q_b         = (const float*)d_in[7];
  const float* in_proj_w   = (const float*)d_in[8];
  const float* in_proj_b   = (const float*)d_in[9];
  const float* out_proj_w  = (const float*)d_in[10];
  const float* out_proj_b  = (const float*)d_in[11];
  const float* syn_w       = (const float*)d_in[12];
  const float* syn_b       = (const float*)d_in[13];
  const float* syn_ln_g    = (const float*)d_in[14];
  const float* syn_ln_b    = (const float*)d_in[15];
  const float* tp1_w       = (const float*)d_in[16];
  const float* tp1_b       = (const float*)d_in[17];
  const float* tp2_w       = (const float*)d_in[18];
  const float* tp2_b       = (const float*)d_in[19];
  const float* start_act   = (const float*)d_in[20];
  const float* start_trace = (const float*)d_in[21];
  const float* decay_action= (const float*)d_in[22];
  const float* decay_out   = (const float*)d_in[23];
  const float* out_w       = (const float*)d_in[24];
  const float* out_b       = (const float*)d_in[25];
  float* dout = (float*)d_out;

  // ---- workspace layout ----
  float* w = (float*)d_ws;
  size_t off = 0;
  auto alloc = [&](size_t n){ n = (n + 3) & ~(size_t)3; float* p = w + off; off += n; return p; };
  float* region0 = alloc((size_t)BGKS*128*NPART);
  float* region1 = alloc((size_t)ROWS*D_IN);
  float* Kmat    = alloc((size_t)ROWS*D_IN);
  float* Vmat    = alloc((size_t)ROWS*D_IN);
  float* trace   = alloc((size_t)BB*TRACE_SLOTS*D_MODEL);
  half_t* sync_oh= (half_t*)alloc((size_t)BB*SO_SZ/2);
  float* a_aP    = alloc((size_t)2*BB*SA_SZ);
  float* act     = alloc((size_t)BB*D_MODEL);
  float* qpart   = alloc((size_t)4*BB*D_IN);
  float* obuf    = alloc((size_t)BB*D_IN);
  float* qfwPad  = alloc((size_t)QPAD*D_IN);
  float* Wf2     = alloc((size_t)D_IN*2048);
  float* bqf     = alloc(D_IN);
  float* bias2   = alloc(2048);
  float* colpart = alloc((size_t)16*2048);
  float* r_a     = alloc(SA_SZ);
  float* r_o     = alloc(SO_SZ);
  int2*  pairsA  = (int2*)alloc(2*SA_SZ);
  int2*  pairsO  = (int2*)alloc(2*SO_SZ);
  half_t* embh   = (half_t*)alloc((size_t)VOCAB*TED/2);
  half_t* kvwh   = (half_t*)alloc((size_t)TED*D_IN/2);
  half_t* Wkh    = (half_t*)alloc((size_t)D_IN*D_IN/2);
  half_t* Wvh    = (half_t*)alloc((size_t)D_IN*D_IN/2);
  half_t* Wqh    = (half_t*)alloc((size_t)D_IN*D_IN/2);
  half_t* oph    = (half_t*)alloc((size_t)D_IN*D_IN/2);
  half_t* synth  = (half_t*)alloc((size_t)D_IN*2048/2);
  half_t* qwh    = (half_t*)alloc((size_t)QPAD*D_IN/2);
  half_t* qfwh   = (half_t*)alloc((size_t)SA_SZ*D_IN/2);
  half_t* Wh     = (half_t*)alloc(((size_t)SO_SZ*WHLD)/2);
  half_t* Ah16   = (half_t*)alloc((size_t)BB*1536/2);
  half_t* Wsynh  = (half_t*)alloc((size_t)1536*2048/2);
  const bool use_syn16 = (off * sizeof(float) <= ws_size);

  half_t* embx_h = (half_t*)region0;
  half_t* kvh    = (half_t*)region0;
  float* part    = region0;
  float* synpart = region0;
  float* kvbuf = region1;
  float* a_o   = region1;

  dim3 blk(256);

  // ---- setup ----
  k_convall<<<(CV7+255)/256, blk, 0, stream>>>(emb, kv_w, in_proj_w, out_proj_w, syn_w, q_w,
                                               embh, kvwh, Wkh, Wvh, Wqh, oph, synth, qwh);
  k_embed_h<<<(ROWS*(TED/8)+255)/256, blk, 0, stream>>>(x, embh, embx_h);
  k_pgemm<<<dim3(8, ROWS/128), blk, 0, stream>>>(embx_h, TED, kvwh, D_IN, kv_b, kvbuf, D_IN, TED/64);
  k_ln_h<<<ROWS, blk, 0, stream>>>(kvbuf, kv_ln_g, kv_ln_b, kvh, D_IN);
  k_pgemm<<<dim3(8, ROWS/128), blk, 0, stream>>>(kvh, D_IN, Wkh, D_IN, in_proj_b+512,  Kmat, D_IN, D_IN/64);
  k_pgemm<<<dim3(8, ROWS/128), blk, 0, stream>>>(kvh, D_IN, Wvh, D_IN, in_proj_b+1024, Vmat, D_IN, D_IN/64);
  k_pgemm<<<dim3(8, QPAD/128), blk, 0, stream>>>(qwh, D_IN, Wqh, D_IN, nullptr, qfwPad, D_IN, D_IN/64);
  k_pgemm<<<dim3(32, D_IN/128), blk, 0, stream>>>(oph, D_IN, synth, 2048, nullptr, Wf2, 2048, D_IN/64);
  k_conv<<<(SA_SZ*D_IN+255)/256, blk, 0, stream>>>(qfwPad, qfwh, SA_SZ*D_IN);
  k_colsumP<<<dim3(2, 16), blk, 0, stream>>>(q_b, in_proj_w, 1536, colpart, D_IN);
  k_colsumR<<<2, blk, 0, stream>>>(colpart, in_proj_b, bqf, D_IN);
  k_colsumP<<<dim3(8, 16), blk, 0, stream>>>(out_proj_b, syn_w, 2048, colpart, 2048);
  k_colsumR<<<8, blk, 0, stream>>>(colpart, syn_b, bias2, 2048);
  k_convw<<<(SO_SZ*WCHUNKS+255)/256, blk, 0, stream>>>(out_w, Wh);
  if (use_syn16)
    k_convsyn<<<(1536*2048+255)/256, blk, 0, stream>>>(Wf2, syn_w, Wsynh);
  k_init_pairs<<<(SA_SZ+255)/256, blk, 0, stream>>>(N_SA, SA_SZ, decay_action, pairsA, r_a);
  k_init_pairs<<<(SO_SZ+255)/256, blk, 0, stream>>>(N_SO, SO_SZ, decay_out,    pairsO, r_o);
  k_init_act<<<(BB*D_MODEL+255)/256, blk, 0, stream>>>(start_act, act, Ah16);
  k_zero<<<(2*BB*SA_SZ+255)/256, blk, 0, stream>>>(a_aP, 2*BB*SA_SZ);
  k_init_trace<<<(BB*MEMN*D_MODEL+255)/256, blk, 0, stream>>>(start_trace, trace);
  k_init_ao<<<dim3((SO_SZ+255)/256, BB), blk, 0, stream>>>(start_act, pairsO, a_o);

  // ---- recurrence with software-pipelined output branch ----
  auto launch_syn = [&](){
    if (use_syn16)
      k_syn16<<<dim3(32, SYNZ), blk, 0, stream>>>(Ah16, Wsynh, synpart);
    else
      k_gemm2srcZ<<<dim3(8, 16, SYNZ), blk, 0, stream>>>(obuf, act, Wf2, syn_w, synpart);
  };
  auto launch_tail = [&](int t){
    k_glu_ln<<<BB, blk, 0, stream>>>(synpart, bias2, syn_ln_g, syn_ln_b,
                                     trace + (size_t)(MEMN+t)*D_MODEL);
    k_neuron<<<(BB*D_MODEL+255)/256, blk, 0, stream>>>(trace, tp1_w, tp1_b, tp2_w, tp2_b,
                                                       act, Ah16, t);
  };

  // prologue t = 0
  k_gemmq<<<dim3(2, 32, 4), blk, 0, stream>>>(act, r_a, pairsA,
      a_aP, a_aP + (size_t)BB*SA_SZ, qfwh, qpart, 0);
  k_attn<<<NB_ATTN, 128, 0, stream>>>(qpart, bqf, Kmat, Vmat, obuf, Ah16);
  launch_syn();
  launch_tail(0);

  for (int t = 1; t < NITER; t++){
    float* aaIn  = a_aP + (size_t)(t & 1)*BB*SA_SZ;
    float* aaOut = a_aP + (size_t)((t+1) & 1)*BB*SA_SZ;
    k_syncO<<<dim3((SO_SZ+255)/256, BB), blk, 0, stream>>>(act, r_o, pairsO, a_o, sync_oh, t-1);
    k_AB1<<<NB_BIG + NB_Q, blk, 0, stream>>>(sync_oh, Wh, part,
        act, r_a, pairsA, aaIn, aaOut, qfwh, qpart, t);
    k_AB2<<<NB_ATTN + BB, 128, 0, stream>>>(qpart, bqf, Kmat, Vmat, obuf, Ah16,
        part, out_b, dout, t-1);
    launch_syn();
    launch_tail(t);
  }

  // epilogue t = 15 output branch
  k_syncO<<<dim3((SO_SZ+255)/256, BB), blk, 0, stream>>>(act, r_o, pairsO, a_o, sync_oh, NITER-1);
  k_bigemm2h<<<dim3(31, BGKS), blk, 0, stream>>>(sync_oh, Wh, part);
  k_out128<<<BB, 128, 0, stream>>>(part, out_b, dout, NITER-1);
}